// Round 2
// baseline (1510.304 us; speedup 1.0000x reference)
//
#include <hip/hip_runtime.h>
#include <hip/hip_bf16.h>
#include <math.h>

#define H_DIM  1152
#define FL_DIM 1152
#define FH_DIM 4608
#define NTOK   32768

typedef __attribute__((ext_vector_type(8))) short bf16x8;
typedef __attribute__((ext_vector_type(4))) float floatx4;
typedef __attribute__((ext_vector_type(4))) unsigned short ushort4v;

__device__ __forceinline__ unsigned short f2bf(float f) {
  union { float f; unsigned int i; } v; v.f = f;
  return (unsigned short)((v.i + 0x7FFFu + ((v.i >> 16) & 1u)) >> 16);
}

// ---------------- fp32 -> bf16 conversion (vectorized, exact grid) ----------
__global__ __launch_bounds__(256) void cvt_kernel(
    const float* __restrict__ in, unsigned short* __restrict__ out, int n4) {
  const int i = blockIdx.x * 256 + threadIdx.x;
  if (i >= n4) return;
  const float4 v = ((const float4*)in)[i];
  ushort4v o;
  o[0] = f2bf(v.x); o[1] = f2bf(v.y); o[2] = f2bf(v.z); o[3] = f2bf(v.w);
  ((ushort4v*)out)[i] = o;
}

// ---------------- router: p1[t] = softmax(x . rw + rb)[heavy] ----------------
__global__ __launch_bounds__(256) void router_kernel(
    const float* __restrict__ x,   // [NTOK, H] fp32
    const float* __restrict__ rw,  // [2, H]
    const float* __restrict__ rb,  // [2]
    float* __restrict__ p1out) {
  const int wave = threadIdx.x >> 6;
  const int lane = threadIdx.x & 63;
  const int tok = blockIdx.x * 4 + wave;
  const float* xr = x + (size_t)tok * H_DIM;
  float s0 = 0.f, s1 = 0.f;
#pragma unroll
  for (int j = 0; j < H_DIM / 64; ++j) {
    const int h = j * 64 + lane;
    const float xv = xr[h];
    s0 += xv * rw[h];
    s1 += xv * rw[H_DIM + h];
  }
  for (int off = 32; off > 0; off >>= 1) {
    s0 += __shfl_down(s0, off);
    s1 += __shfl_down(s1, off);
  }
  if (lane == 0) {
    const float l0 = s0 + rb[0];
    const float l1 = s1 + rb[1];
    p1out[tok] = 1.f / (1.f + expf(l0 - l1));
  }
}

// ------------- shared GEMM building blocks (128x128 tile, BK=64) -------------
// LDS: 128 rows x 8 chunks of 16B; chunk column XOR-swizzled by (row&7) so the
// ds_read_b128 fragment reads are 2-way bank-aliased (free) instead of 16-way.
// global_load_lds destination is wave-uniform base + lane*16 (HW requirement).
__device__ __forceinline__ void stage_tile(const unsigned short* __restrict__ g0,
                                           int lda, unsigned short* l0, int tid) {
  const int w = tid >> 6;
#pragma unroll
  for (int i = 0; i < 4; ++i) {
    const int c = i * 256 + tid;     // linear 16B-chunk index, 1024 total
    const int row = c >> 3;
    const int jg = (c & 7) ^ (row & 7);
    const unsigned short* g = g0 + (size_t)row * lda + jg * 8;
    unsigned short* lp = l0 + (size_t)(i * 4 + w) * 512;  // wave-uniform base
    __builtin_amdgcn_global_load_lds((const __attribute__((address_space(1))) void*)g,
                                     (__attribute__((address_space(3))) void*)lp,
                                     16, 0, 0);
  }
}

__device__ __forceinline__ void mma_tile(const unsigned short* As, const unsigned short* Bs,
                                         floatx4 acc[4][4], int wm, int wn, int quad, int l16) {
#pragma unroll
  for (int kk = 0; kk < 2; ++kk) {
    bf16x8 af[4], bfr[4];
#pragma unroll
    for (int mi = 0; mi < 4; ++mi) {
      const int row = wm * 64 + mi * 16 + l16;
      const int ch = (kk * 4 + quad) ^ (row & 7);
      af[mi] = *(const bf16x8*)(As + row * 64 + ch * 8);
    }
#pragma unroll
    for (int ni = 0; ni < 4; ++ni) {
      const int row = wn * 64 + ni * 16 + l16;
      const int ch = (kk * 4 + quad) ^ (row & 7);
      bfr[ni] = *(const bf16x8*)(Bs + row * 64 + ch * 8);
    }
#pragma unroll
    for (int mi = 0; mi < 4; ++mi)
#pragma unroll
      for (int ni = 0; ni < 4; ++ni)
        acc[mi][ni] = __builtin_amdgcn_mfma_f32_16x16x32_bf16(af[mi], bfr[ni], acc[mi][ni], 0, 0, 0);
  }
}

// --------- GEMM1: Hout[t,f] = scale * gelu(sum_h X[t,h]W1[f,h] + b1[f]) ------
__global__ __launch_bounds__(256, 2) void gemm1_kernel(
    const unsigned short* __restrict__ X,    // [C, H] bf16 (chunk)
    const unsigned short* __restrict__ W1,   // [F, H] bf16
    const float* __restrict__ b1,            // [F] fp32
    const float* __restrict__ p1,            // [C] chunk probs
    unsigned short* __restrict__ Hout,       // [C, F] bf16
    int F, int use_p1) {
  __shared__ __align__(16) unsigned short As[128 * 64];
  __shared__ __align__(16) unsigned short Bs[128 * 64];
  const int tid = threadIdx.x;
  const int w = tid >> 6, lane = tid & 63;
  const int wm = w >> 1, wn = w & 1;
  const int quad = lane >> 4, l16 = lane & 15;
  const int tm = blockIdx.y * 128;
  const int tn = blockIdx.x * 128;

  floatx4 acc[4][4];
#pragma unroll
  for (int i = 0; i < 4; ++i)
#pragma unroll
    for (int j = 0; j < 4; ++j) acc[i][j] = (floatx4){0.f, 0.f, 0.f, 0.f};

  const unsigned short* Abase = X + (size_t)tm * H_DIM;
  const unsigned short* Bbase = W1 + (size_t)tn * H_DIM;

  for (int kt = 0; kt < H_DIM / 64; ++kt) {
    __syncthreads();
    stage_tile(Abase + kt * 64, H_DIM, As, tid);
    stage_tile(Bbase + kt * 64, H_DIM, Bs, tid);
    __syncthreads();
    mma_tile(As, Bs, acc, wm, wn, quad, l16);
  }

  float bias[4];
#pragma unroll
  for (int ni = 0; ni < 4; ++ni) bias[ni] = b1[tn + wn * 64 + ni * 16 + l16];

#pragma unroll
  for (int mi = 0; mi < 4; ++mi) {
#pragma unroll
    for (int r = 0; r < 4; ++r) {
      const int gtok = tm + wm * 64 + mi * 16 + quad * 4 + r;
      const float pv = p1[gtok];
      const float scale = use_p1 ? pv : (1.f - pv);
#pragma unroll
      for (int ni = 0; ni < 4; ++ni) {
        const int col = tn + wn * 64 + ni * 16 + l16;
        const float v = acc[mi][ni][r] + bias[ni];
        const float g = 0.5f * v * (1.f + erff(v * 0.70710678118f));
        Hout[(size_t)gtok * F + col] = f2bf(g * scale);
      }
    }
  }
}

// -- GEMM2: out[t,h] = Hl.W2l^T + Hh.W2h^T + (1-p1)b2l + p1*b2h (K = 5760) ---
__global__ __launch_bounds__(256, 2) void gemm2_kernel(
    const unsigned short* __restrict__ Hl,   // [C, FL] bf16
    const unsigned short* __restrict__ Hh,   // [C, FH] bf16
    const unsigned short* __restrict__ W2l,  // [H, FL] bf16
    const unsigned short* __restrict__ W2h,  // [H, FH] bf16
    const float* __restrict__ b2l,           // [H] fp32
    const float* __restrict__ b2h,           // [H] fp32
    const float* __restrict__ p1,            // [C]
    float* __restrict__ Out) {               // [C, H] fp32
  __shared__ __align__(16) unsigned short As[128 * 64];
  __shared__ __align__(16) unsigned short Bs[128 * 64];
  const int tid = threadIdx.x;
  const int w = tid >> 6, lane = tid & 63;
  const int wm = w >> 1, wn = w & 1;
  const int quad = lane >> 4, l16 = lane & 15;
  const int tm = blockIdx.y * 128;
  const int tn = blockIdx.x * 128;

  floatx4 acc[4][4];
#pragma unroll
  for (int i = 0; i < 4; ++i)
#pragma unroll
    for (int j = 0; j < 4; ++j) acc[i][j] = (floatx4){0.f, 0.f, 0.f, 0.f};

  const int KT1 = FL_DIM / 64;              // 18
  const int KTALL = KT1 + FH_DIM / 64;      // 90
  for (int kt = 0; kt < KTALL; ++kt) {
    const unsigned short* Ab;
    const unsigned short* Bb;
    int lda;
    if (kt < KT1) {
      Ab = Hl + (size_t)tm * FL_DIM + kt * 64;
      Bb = W2l + (size_t)tn * FL_DIM + kt * 64;
      lda = FL_DIM;
    } else {
      const int k2 = kt - KT1;
      Ab = Hh + (size_t)tm * FH_DIM + k2 * 64;
      Bb = W2h + (size_t)tn * FH_DIM + k2 * 64;
      lda = FH_DIM;
    }
    __syncthreads();
    stage_tile(Ab, lda, As, tid);
    stage_tile(Bb, lda, Bs, tid);
    __syncthreads();
    mma_tile(As, Bs, acc, wm, wn, quad, l16);
  }

  float bl[4], bh[4];
#pragma unroll
  for (int ni = 0; ni < 4; ++ni) {
    const int col = tn + wn * 64 + ni * 16 + l16;
    bl[ni] = b2l[col];
    bh[ni] = b2h[col];
  }

#pragma unroll
  for (int mi = 0; mi < 4; ++mi) {
#pragma unroll
    for (int r = 0; r < 4; ++r) {
      const int gtok = tm + wm * 64 + mi * 16 + quad * 4 + r;
      const float pv = p1[gtok];
#pragma unroll
      for (int ni = 0; ni < 4; ++ni) {
        const int col = tn + wn * 64 + ni * 16 + l16;
        Out[(size_t)gtok * H_DIM + col] = acc[mi][ni][r] + bl[ni] + pv * (bh[ni] - bl[ni]);
      }
    }
  }
}

extern "C" void kernel_launch(void* const* d_in, const int* in_sizes, int n_in,
                              void* d_out, int out_size, void* d_ws, size_t ws_size,
                              hipStream_t stream) {
  const float* x   = (const float*)d_in[0];
  const float* rw  = (const float*)d_in[1];
  const float* rb  = (const float*)d_in[2];
  const float* lw1 = (const float*)d_in[3];
  const float* lb1 = (const float*)d_in[4];
  const float* lw2 = (const float*)d_in[5];
  const float* lb2 = (const float*)d_in[6];
  const float* hw1 = (const float*)d_in[7];
  const float* hb1 = (const float*)d_in[8];
  const float* hw2 = (const float*)d_in[9];
  const float* hb2 = (const float*)d_in[10];
  float* out = (float*)d_out;

  // ---- workspace layout (all offsets 16B-aligned) ----
  const size_t N_LW = (size_t)FL_DIM * H_DIM;   // 1,327,104
  const size_t N_HW = (size_t)FH_DIM * H_DIM;   // 5,308,416
  char* p = (char*)d_ws;
  float* p1 = (float*)p;                  p += (size_t)NTOK * 4;
  unsigned short* lw1b = (unsigned short*)p; p += N_LW * 2;
  unsigned short* hw1b = (unsigned short*)p; p += N_HW * 2;
  unsigned short* lw2b = (unsigned short*)p; p += N_LW * 2;
  unsigned short* hw2b = (unsigned short*)p; p += N_HW * 2;
  const size_t fixed = (size_t)(p - (char*)d_ws);

  // tokens per chunk: xc (C*H*2) + hl (C*FL*2) + hh (C*FH*2) = C*13824 bytes
  int C = NTOK;
  while (C > 128 && fixed + (size_t)C * 13824 > ws_size) C >>= 1;
  unsigned short* xc = (unsigned short*)p;
  unsigned short* hl = xc + (size_t)C * H_DIM;
  unsigned short* hh = hl + (size_t)C * FL_DIM;

  // ---- weight conversions (fp32 -> bf16), once per call ----
  cvt_kernel<<<(int)(N_LW / 1024), 256, 0, stream>>>(lw1, lw1b, (int)(N_LW / 4));
  cvt_kernel<<<(int)(N_HW / 1024), 256, 0, stream>>>(hw1, hw1b, (int)(N_HW / 4));
  cvt_kernel<<<(int)(N_LW / 1024), 256, 0, stream>>>(lw2, lw2b, (int)(N_LW / 4));
  cvt_kernel<<<(int)(N_HW / 1024), 256, 0, stream>>>(hw2, hw2b, (int)(N_HW / 4));

  router_kernel<<<NTOK / 4, 256, 0, stream>>>(x, rw, rb, p1);

  for (int c0 = 0; c0 < NTOK; c0 += C) {
    const size_t nX = (size_t)C * H_DIM;
    cvt_kernel<<<(int)(nX / 1024), 256, 0, stream>>>(x + (size_t)c0 * H_DIM, xc, (int)(nX / 4));
    gemm1_kernel<<<dim3(FL_DIM / 128, C / 128), 256, 0, stream>>>(
        xc, lw1b, lb1, p1 + c0, hl, FL_DIM, 0);
    gemm1_kernel<<<dim3(FH_DIM / 128, C / 128), 256, 0, stream>>>(
        xc, hw1b, hb1, p1 + c0, hh, FH_DIM, 1);
    gemm2_kernel<<<dim3(H_DIM / 128, C / 128), 256, 0, stream>>>(
        hl, hh, lw2b, hw2b, lb2, hb2, p1 + c0, out + (size_t)c0 * H_DIM);
  }
}

// Round 3
// 1293.669 us; speedup vs baseline: 1.1675x; 1.1675x over previous
//
#include <hip/hip_runtime.h>
#include <hip/hip_bf16.h>
#include <math.h>

#define H_DIM  1152
#define FL_DIM 1152
#define FH_DIM 4608
#define NTOK   32768

typedef __attribute__((ext_vector_type(8))) short bf16x8;
typedef __attribute__((ext_vector_type(4))) float floatx4;
typedef __attribute__((ext_vector_type(4))) unsigned short ushort4v;

__device__ __forceinline__ unsigned short f2bf(float f) {
  union { float f; unsigned int i; } v; v.f = f;
  return (unsigned short)((v.i + 0x7FFFu + ((v.i >> 16) & 1u)) >> 16);
}

// ---------------- fp32 -> bf16 conversion (weights) -------------------------
__global__ __launch_bounds__(256) void cvt_kernel(
    const float* __restrict__ in, unsigned short* __restrict__ out, int n4) {
  const int i = blockIdx.x * 256 + threadIdx.x;
  if (i >= n4) return;
  const float4 v = ((const float4*)in)[i];
  ushort4v o;
  o[0] = f2bf(v.x); o[1] = f2bf(v.y); o[2] = f2bf(v.z); o[3] = f2bf(v.w);
  ((ushort4v*)out)[i] = o;
}

// ------- router + x cvt: p1[t] = sigmoid(l1-l0); xb = bf16(x) ---------------
__global__ __launch_bounds__(256) void router_cvt_kernel(
    const float* __restrict__ x,   // [NTOK, H] fp32
    const float* __restrict__ rw,  // [2, H]
    const float* __restrict__ rb,  // [2]
    float* __restrict__ p1out,     // [NTOK]
    unsigned short* __restrict__ xb) {  // [NTOK, H] bf16
  const int wave = threadIdx.x >> 6;
  const int lane = threadIdx.x & 63;
  const int tok = blockIdx.x * 4 + wave;
  const float* xr = x + (size_t)tok * H_DIM;
  unsigned short* xo = xb + (size_t)tok * H_DIM;
  float s0 = 0.f, s1 = 0.f;
#pragma unroll
  for (int j = 0; j < H_DIM / 64; ++j) {
    const int h = j * 64 + lane;
    const float xv = xr[h];
    xo[h] = f2bf(xv);
    s0 += xv * rw[h];
    s1 += xv * rw[H_DIM + h];
  }
  for (int off = 32; off > 0; off >>= 1) {
    s0 += __shfl_down(s0, off);
    s1 += __shfl_down(s1, off);
  }
  if (lane == 0) {
    const float l0 = s0 + rb[0];
    const float l1 = s1 + rb[1];
    p1out[tok] = 1.f / (1.f + expf(l0 - l1));
  }
}

// ------------- shared GEMM building blocks (128x128 tile, BK=64) -------------
// LDS: 128 rows x 8 chunks of 16B; chunk column XOR-swizzled by (row&7) so the
// ds_read_b128 fragment reads are 2-way bank-aliased (free) instead of 16-way.
// global_load_lds destination is wave-uniform base + lane*16 (HW requirement).
__device__ __forceinline__ void stage_tile(const unsigned short* __restrict__ g0,
                                           int lda, unsigned short* l0, int tid) {
  const int w = tid >> 6;
#pragma unroll
  for (int i = 0; i < 4; ++i) {
    const int c = i * 256 + tid;     // linear 16B-chunk index, 1024 total
    const int row = c >> 3;
    const int jg = (c & 7) ^ (row & 7);
    const unsigned short* g = g0 + (size_t)row * lda + jg * 8;
    unsigned short* lp = l0 + (size_t)(i * 4 + w) * 512;  // wave-uniform base
    __builtin_amdgcn_global_load_lds((const __attribute__((address_space(1))) void*)g,
                                     (__attribute__((address_space(3))) void*)lp,
                                     16, 0, 0);
  }
}

__device__ __forceinline__ void mma_tile(const unsigned short* As, const unsigned short* Bs,
                                         floatx4 acc[4][4], int wm, int wn, int quad, int l16) {
#pragma unroll
  for (int kk = 0; kk < 2; ++kk) {
    bf16x8 af[4], bfr[4];
#pragma unroll
    for (int mi = 0; mi < 4; ++mi) {
      const int row = wm * 64 + mi * 16 + l16;
      const int ch = (kk * 4 + quad) ^ (row & 7);
      af[mi] = *(const bf16x8*)(As + row * 64 + ch * 8);
    }
#pragma unroll
    for (int ni = 0; ni < 4; ++ni) {
      const int row = wn * 64 + ni * 16 + l16;
      const int ch = (kk * 4 + quad) ^ (row & 7);
      bfr[ni] = *(const bf16x8*)(Bs + row * 64 + ch * 8);
    }
#pragma unroll
    for (int mi = 0; mi < 4; ++mi)
#pragma unroll
      for (int ni = 0; ni < 4; ++ni)
        acc[mi][ni] = __builtin_amdgcn_mfma_f32_16x16x32_bf16(af[mi], bfr[ni], acc[mi][ni], 0, 0, 0);
  }
}

// XCD-grouped swizzle: consecutive block IDs round-robin over 8 XCDs, so give
// each XCD a contiguous band of M-tiles across all N-tiles. All N-tiles of a
// given M-tile then run on ONE XCD, adjacent in time -> A-tile L2/LLC reuse.
__device__ __forceinline__ void swizzle(int b, int gm, int gn, int& m, int& n) {
  const int xcd = b & 7;
  const int idx = b >> 3;
  const int mloc = idx / gn;
  n = idx - mloc * gn;
  m = xcd * (gm >> 3) + mloc;
}

// - GEMM1 fused: Hl/Hh[t,f] = scale * gelu(x.W1^T + b1), scale = (1-p) or p --
__global__ __launch_bounds__(256, 2) void gemm1_fused_kernel(
    const unsigned short* __restrict__ Xb,   // [C, H] bf16
    const unsigned short* __restrict__ W1l,  // [FL, H] bf16
    const unsigned short* __restrict__ W1h,  // [FH, H] bf16
    const float* __restrict__ b1l,           // [FL] fp32
    const float* __restrict__ b1h,           // [FH] fp32
    const float* __restrict__ p1,            // [C]
    unsigned short* __restrict__ Hl,         // [C, FL] bf16
    unsigned short* __restrict__ Hh,         // [C, FH] bf16
    int gm) {
  __shared__ __align__(16) unsigned short As[128 * 64];
  __shared__ __align__(16) unsigned short Bs[128 * 64];
  const int tid = threadIdx.x;
  const int w = tid >> 6, lane = tid & 63;
  const int wm = w >> 1, wn = w & 1;
  const int quad = lane >> 4, l16 = lane & 15;

  int m, n;
  swizzle(blockIdx.x, gm, 45, m, n);           // 9 light + 36 heavy N-tiles
  const int tm = m * 128;
  const bool heavy = n >= 9;
  const int nl = heavy ? n - 9 : n;
  const int tn = nl * 128;
  const int F = heavy ? FH_DIM : FL_DIM;
  const unsigned short* W = heavy ? W1h : W1l;
  const float* bias_p = heavy ? b1h : b1l;
  unsigned short* Hout = heavy ? Hh : Hl;

  floatx4 acc[4][4];
#pragma unroll
  for (int i = 0; i < 4; ++i)
#pragma unroll
    for (int j = 0; j < 4; ++j) acc[i][j] = (floatx4){0.f, 0.f, 0.f, 0.f};

  const unsigned short* Abase = Xb + (size_t)tm * H_DIM;
  const unsigned short* Bbase = W + (size_t)tn * H_DIM;

  for (int kt = 0; kt < H_DIM / 64; ++kt) {
    __syncthreads();
    stage_tile(Abase + kt * 64, H_DIM, As, tid);
    stage_tile(Bbase + kt * 64, H_DIM, Bs, tid);
    __syncthreads();
    mma_tile(As, Bs, acc, wm, wn, quad, l16);
  }

  float bias[4];
#pragma unroll
  for (int ni = 0; ni < 4; ++ni) bias[ni] = bias_p[tn + wn * 64 + ni * 16 + l16];

#pragma unroll
  for (int mi = 0; mi < 4; ++mi) {
#pragma unroll
    for (int r = 0; r < 4; ++r) {
      const int gtok = tm + wm * 64 + mi * 16 + quad * 4 + r;
      const float pv = p1[gtok];
      const float scale = heavy ? pv : (1.f - pv);
#pragma unroll
      for (int ni = 0; ni < 4; ++ni) {
        const int col = tn + wn * 64 + ni * 16 + l16;
        const float v = acc[mi][ni][r] + bias[ni];
        const float g = 0.5f * v * (1.f + erff(v * 0.70710678118f));
        Hout[(size_t)gtok * F + col] = f2bf(g * scale);
      }
    }
  }
}

// -- GEMM2: out[t,h] = Hl.W2l^T + Hh.W2h^T + (1-p1)b2l + p1*b2h (K = 5760) ---
__global__ __launch_bounds__(256, 2) void gemm2_kernel(
    const unsigned short* __restrict__ Hl,   // [C, FL] bf16
    const unsigned short* __restrict__ Hh,   // [C, FH] bf16
    const unsigned short* __restrict__ W2l,  // [H, FL] bf16
    const unsigned short* __restrict__ W2h,  // [H, FH] bf16
    const float* __restrict__ b2l,           // [H] fp32
    const float* __restrict__ b2h,           // [H] fp32
    const float* __restrict__ p1,            // [C]
    float* __restrict__ Out,                 // [C, H] fp32
    int gm) {
  __shared__ __align__(16) unsigned short As[128 * 64];
  __shared__ __align__(16) unsigned short Bs[128 * 64];
  const int tid = threadIdx.x;
  const int w = tid >> 6, lane = tid & 63;
  const int wm = w >> 1, wn = w & 1;
  const int quad = lane >> 4, l16 = lane & 15;

  int m, n;
  swizzle(blockIdx.x, gm, 9, m, n);
  const int tm = m * 128;
  const int tn = n * 128;

  floatx4 acc[4][4];
#pragma unroll
  for (int i = 0; i < 4; ++i)
#pragma unroll
    for (int j = 0; j < 4; ++j) acc[i][j] = (floatx4){0.f, 0.f, 0.f, 0.f};

  const int KT1 = FL_DIM / 64;              // 18
  const int KTALL = KT1 + FH_DIM / 64;      // 90
  for (int kt = 0; kt < KTALL; ++kt) {
    const unsigned short* Ab;
    const unsigned short* Bb;
    int lda;
    if (kt < KT1) {
      Ab = Hl + (size_t)tm * FL_DIM + kt * 64;
      Bb = W2l + (size_t)tn * FL_DIM + kt * 64;
      lda = FL_DIM;
    } else {
      const int k2 = kt - KT1;
      Ab = Hh + (size_t)tm * FH_DIM + k2 * 64;
      Bb = W2h + (size_t)tn * FH_DIM + k2 * 64;
      lda = FH_DIM;
    }
    __syncthreads();
    stage_tile(Ab, lda, As, tid);
    stage_tile(Bb, lda, Bs, tid);
    __syncthreads();
    mma_tile(As, Bs, acc, wm, wn, quad, l16);
  }

  float bl[4], bh[4];
#pragma unroll
  for (int ni = 0; ni < 4; ++ni) {
    const int col = tn + wn * 64 + ni * 16 + l16;
    bl[ni] = b2l[col];
    bh[ni] = b2h[col];
  }

#pragma unroll
  for (int mi = 0; mi < 4; ++mi) {
#pragma unroll
    for (int r = 0; r < 4; ++r) {
      const int gtok = tm + wm * 64 + mi * 16 + quad * 4 + r;
      const float pv = p1[gtok];
#pragma unroll
      for (int ni = 0; ni < 4; ++ni) {
        const int col = tn + wn * 64 + ni * 16 + l16;
        Out[(size_t)gtok * H_DIM + col] = acc[mi][ni][r] + bl[ni] + pv * (bh[ni] - bl[ni]);
      }
    }
  }
}

extern "C" void kernel_launch(void* const* d_in, const int* in_sizes, int n_in,
                              void* d_out, int out_size, void* d_ws, size_t ws_size,
                              hipStream_t stream) {
  const float* x   = (const float*)d_in[0];
  const float* rw  = (const float*)d_in[1];
  const float* rb  = (const float*)d_in[2];
  const float* lw1 = (const float*)d_in[3];
  const float* lb1 = (const float*)d_in[4];
  const float* lw2 = (const float*)d_in[5];
  const float* lb2 = (const float*)d_in[6];
  const float* hw1 = (const float*)d_in[7];
  const float* hb1 = (const float*)d_in[8];
  const float* hw2 = (const float*)d_in[9];
  const float* hb2 = (const float*)d_in[10];
  float* out = (float*)d_out;

  // ---- workspace layout ----
  const size_t N_LW = (size_t)FL_DIM * H_DIM;
  const size_t N_HW = (size_t)FH_DIM * H_DIM;
  char* p = (char*)d_ws;
  float* p1 = (float*)p;                     p += (size_t)NTOK * 4;
  unsigned short* lw1b = (unsigned short*)p; p += N_LW * 2;
  unsigned short* hw1b = (unsigned short*)p; p += N_HW * 2;
  unsigned short* lw2b = (unsigned short*)p; p += N_LW * 2;
  unsigned short* hw2b = (unsigned short*)p; p += N_HW * 2;
  unsigned short* xb   = (unsigned short*)p; p += (size_t)NTOK * H_DIM * 2;
  const size_t fixed = (size_t)(p - (char*)d_ws);

  // tokens per chunk: hl (C*FL*2) + hh (C*FH*2) = C*11520 bytes
  int C = NTOK;
  while (C > 1024 && fixed + (size_t)C * 11520 > ws_size) C >>= 1;
  unsigned short* hl = (unsigned short*)p;
  unsigned short* hh = hl + (size_t)C * FL_DIM;

  // ---- weight conversions (fp32 -> bf16) ----
  cvt_kernel<<<(int)(N_LW / 1024), 256, 0, stream>>>(lw1, lw1b, (int)(N_LW / 4));
  cvt_kernel<<<(int)(N_HW / 1024), 256, 0, stream>>>(hw1, hw1b, (int)(N_HW / 4));
  cvt_kernel<<<(int)(N_LW / 1024), 256, 0, stream>>>(lw2, lw2b, (int)(N_LW / 4));
  cvt_kernel<<<(int)(N_HW / 1024), 256, 0, stream>>>(hw2, hw2b, (int)(N_HW / 4));

  router_cvt_kernel<<<NTOK / 4, 256, 0, stream>>>(x, rw, rb, p1, xb);

  for (int c0 = 0; c0 < NTOK; c0 += C) {
    const int gm = C / 128;
    gemm1_fused_kernel<<<gm * 45, 256, 0, stream>>>(
        xb + (size_t)c0 * H_DIM, lw1b, hw1b, lb1, hb1, p1 + c0, hl, hh, gm);
    gemm2_kernel<<<gm * 9, 256, 0, stream>>>(
        hl, hh, lw2b, hw2b, lb2, hb2, p1 + c0, out + (size_t)c0 * H_DIM, gm);
  }
}